// Round 12
// baseline (7929.876 us; speedup 1.0000x reference)
//
#include <hip/hip_runtime.h>
#include <math.h>

// ESN reservoir, persistent kernel, round 30: XCD-local (intra-L2) exchange
// with single-decider consensus; uniform fallback = r27 exactly.
//
// r28/r29 established: at MALL scope, detect is at its floor (sample sees
// state issue+RT/2 => lag >= ~450cy past visibility; r27's adaptive sample
// ~= floor). Every remaining term scales with the ~900cy MALL RT.
// r30 changes the CONSTANT: groups form per-XCD so the exchange coherence
// point is the XCD-shared L2 (~250cy RT). CDNA L1 is write-through: plain/
// sc0 stores land in L2; sc0 loads bypass L1 and read the same L2.
//
// r19's failure was decision machinery (per-block decision -> mixed mode),
// not the cache claim (its WRITE_SIZE=262MB proves the fast path never ran).
// r30's fixes:
//  1. discovery: XCC_ID (hwreg 20, m09-verified) + per-XCD atomic slot.
//  2. probe: sc0 store + bounded sc0 poll of the group's 32 probe words.
//  3. consensus: all blocks report (mapping ok, probe ok) UC; block 0
//     aggregates 256 reports, publishes ONE decision word UC; all blocks
//     poll it (timeout 100x decision latency) => mixed mode structurally
//     excluded. Any anomaly => uniform slow = r27 (+~50us prologue).
// Stale-L2 across dispatches: kernel-boundary acquire invalidates L2s;
// within a dispatch tags only increase. Bounded spins: never hang.
//
// Main loop = r27 verbatim (best, 6280us) with policy-parameterized cache
// ops + r29's fast_tanh (tanh = 1 - 2*rcp(e^{2x}+1), err ~1e-6 pre-quant).

#define RDIM   2048
#define BATCH  16
#define TSTEPS 2048
#define NIN    3
#define NOUT   3
#define NBLK   256
#define NTHR   512

typedef unsigned u32x2 __attribute__((ext_vector_type(2)));

// workspace layout (dwords)
#define HT0_DW     0            // [8 groups][2 batches][1024] tagged h dwords
#define HT1_DW     16384
#define DISC_DW    32768        // 8 per-XCD claim counters
#define RPT_DW     32776        // 256 mapping reports (1 ok / 2 bad)
#define PPT_DW     33032        // 256 probe reports   (1 ok / 2 bad)
#define PRB_DW     33288        // 256 probe words
#define DEC_DW     33544        // decision (1 slow / 2 fast)
#define WS_USED_DW 33552

#define POLL_MAX   (1L << 14)

#define TAGOK(a, b, t) (((a)[0] >> 16) == (t) && ((a)[1] >> 16) == (t) && \
                        ((b)[0] >> 16) == (t) && ((b)[1] >> 16) == (t))

__device__ __forceinline__ unsigned sysld(const unsigned* p) {
    return __hip_atomic_load(p, __ATOMIC_RELAXED, __HIP_MEMORY_SCOPE_SYSTEM);
}
__device__ __forceinline__ void sysst(unsigned* p, unsigned v) {
    __hip_atomic_store(p, v, __ATOMIC_RELAXED, __HIP_MEMORY_SCOPE_SYSTEM);
}
// L2-scope ops (probe + fast mode): sc0 = bypass L1, serve at XCD L2.
__device__ __forceinline__ void st1_l2(unsigned* p, unsigned v) {
    asm volatile("global_store_dword %0, %1, off sc0" :: "v"(p), "v"(v) : "memory");
}
__device__ __forceinline__ unsigned ld1_l2(const unsigned* p) {
    unsigned d;
    asm volatile("global_load_dword %0, %1, off sc0\n\ts_waitcnt vmcnt(0)"
                 : "=v"(d) : "v"(p) : "memory");
    return d;
}
// policy-parameterized tagged ops (fast: sc0 / slow: sc0 sc1)
__device__ __forceinline__ void pf_issue_p(u32x2& a, u32x2& b,
                                           const unsigned* pA, const unsigned* pB,
                                           bool fast) {
    if (fast)
        asm volatile("global_load_dwordx2 %0, %2, off sc0\n\t"
                     "global_load_dwordx2 %1, %3, off sc0"
                     : "+v"(a), "+v"(b) : "v"(pA), "v"(pB) : "memory");
    else
        asm volatile("global_load_dwordx2 %0, %2, off sc0 sc1\n\t"
                     "global_load_dwordx2 %1, %3, off sc0 sc1"
                     : "+v"(a), "+v"(b) : "v"(pA), "v"(pB) : "memory");
}
__device__ __forceinline__ void ld_poll_p(u32x2& a, u32x2& b,
                                          const unsigned* pA, const unsigned* pB,
                                          bool fast) {
    if (fast)
        asm volatile("global_load_dwordx2 %0, %2, off sc0\n\t"
                     "global_load_dwordx2 %1, %3, off sc0\n\t"
                     "s_waitcnt vmcnt(0)"
                     : "+v"(a), "+v"(b) : "v"(pA), "v"(pB) : "memory");
    else
        asm volatile("global_load_dwordx2 %0, %2, off sc0 sc1\n\t"
                     "global_load_dwordx2 %1, %3, off sc0 sc1\n\t"
                     "s_waitcnt vmcnt(0)"
                     : "+v"(a), "+v"(b) : "v"(pA), "v"(pB) : "memory");
}
__device__ __forceinline__ void st1_p(unsigned* p, unsigned v, bool fast) {
    if (fast)
        asm volatile("global_store_dword %0, %1, off sc0" :: "v"(p), "v"(v) : "memory");
    else
        asm volatile("global_store_dword %0, %1, off sc0 sc1" :: "v"(p), "v"(v) : "memory");
}

__device__ __forceinline__ int q8(float v) {          // round, clamp [-127,127]
    float c = fminf(127.f, fmaxf(-127.f, v));
    return (int)__builtin_rintf(c);
}
__device__ __forceinline__ float fast_tanh(float x) {
    float e2 = __expf(2.f * x);
    return 1.f - 2.f * __builtin_amdgcn_rcpf(e2 + 1.f);
}
__device__ __forceinline__ unsigned pack4(int a, int b, int c, int d) {
    return (a & 0xff) | ((b & 0xff) << 8) | ((c & 0xff) << 16) | ((d & 0xff) << 24);
}
__device__ __forceinline__ int dot4i(unsigned a, unsigned b, int c) {
#if __has_builtin(__builtin_amdgcn_sdot4)
    return __builtin_amdgcn_sdot4((int)a, (int)b, c, false);
#else
    c += (int)(signed char)(a) * (int)(signed char)(b);
    c += (int)(signed char)(a >> 8)  * (int)(signed char)(b >> 8);
    c += (int)(signed char)(a >> 16) * (int)(signed char)(b >> 16);
    c += (int)(signed char)(a >> 24) * (int)(signed char)(b >> 24);
    return c;
#endif
}
__device__ __forceinline__ int dot16(uint4 wq, uint4 hq, int c) {
    c = dot4i(wq.x, hq.x, c);
    c = dot4i(wq.y, hq.y, c);
    c = dot4i(wq.z, hq.z, c);
    c = dot4i(wq.w, hq.w, c);
    return c;
}

extern "C" __global__ void __launch_bounds__(NTHR, 1) esn_persist(
    const float* __restrict__ W,       // [R,R] fp32
    const float* __restrict__ Win,     // [R,3]
    const float* __restrict__ x,       // [B,T,3]
    const float* __restrict__ Wout,    // [3,R]
    const float* __restrict__ bout,    // [3]
    unsigned* wsu,                     // workspace (dwords, see layout)
    float* __restrict__ out)           // [B,T,3]
{
    __shared__ int red[2][8][8][17];               // [par][wave][rgrp][rr*2+b] padded
    __shared__ __align__(16) unsigned hstage[2][2][512];  // [par][batch][payload dw]
    __shared__ float wscale[64];                   // per-row W scale (m/127)
    __shared__ int s_map[3];                       // xcc, slot, fast
    extern __shared__ unsigned wlds[];             // 128 KB: W int8, swizzled granules

    const int tid  = threadIdx.x;
    const int lane = tid & 63;
    const int w    = tid >> 6;               // wave 0..7
    const int blk  = blockIdx.x;
    const int kslot = lane >> 3;             // 0..7: k sub-slice within wave
    const int rgrp  = lane & 7;              // 0..7: row octet within block

    // ================= prologue: discovery / probe / consensus =============
    if (tid == 0) {
        unsigned xcc;
        asm volatile("s_getreg_b32 %0, hwreg(20, 0, 32)" : "=s"(xcc)); // XCC_ID
        xcc &= 7u;
        unsigned slot = atomicAdd(&wsu[DISC_DW + xcc], 1u);
        __builtin_amdgcn_s_waitcnt(0);           // claim performed before report
        sysst(&wsu[RPT_DW + blk], (slot < 32u) ? 1u : 2u);
        s_map[0] = (int)xcc;
        s_map[1] = (int)(slot & 31u);
    }
    __syncthreads();
    const int gx = s_map[0], rgx = s_map[1];

    // probe intra-group sc0 visibility (bounded ~0.4ms; dispatch skew ~us)
    if (tid == 0) st1_l2(&wsu[PRB_DW + gx * 32 + rgx], 0xC0DEu);
    if (w == 0) {
        bool got = false;
        for (long r = 0; r < (1L << 13) && !got; ++r) {
            unsigned v = 0xC0DEu;
            if (lane < 32) v = ld1_l2(&wsu[PRB_DW + gx * 32 + lane]);
            got = (bool)__all((int)(v == 0xC0DEu));
            if (!got) __builtin_amdgcn_s_sleep(2);
        }
        if (lane == 0) sysst(&wsu[PPT_DW + blk], got ? 1u : 2u);
    }
    // block 0: aggregate 256 (mapping, probe) reports -> ONE decision word
    if (blk == 0) {
        bool ok = true;
        if (tid < NBLK) {
            unsigned m = 0, p = 0;
            for (long r = 0; r < (1L << 20) && (m == 0 || p == 0); ++r) {
                m = sysld(&wsu[RPT_DW + tid]);
                p = sysld(&wsu[PPT_DW + tid]);
                if (m == 0 || p == 0) __builtin_amdgcn_s_sleep(2);
            }
            ok = (m == 1u && p == 1u);
        }
        ok = (bool)__syncthreads_and((int)ok);
        if (tid == 0) sysst(&wsu[DEC_DW], ok ? 2u : 1u);
    }
    if (tid == 0) {                              // all blocks read SAME word
        unsigned d = 0;
        for (long r = 0; r < (1L << 20) && d == 0; ++r) {
            d = sysld(&wsu[DEC_DW]);
            if (d == 0) __builtin_amdgcn_s_sleep(2);
        }
        s_map[2] = (d == 2u) ? 1 : 0;            // timeout/anomaly -> slow
    }
    __syncthreads();
    const bool fastp = s_map[2] != 0;            // uniform across ALL blocks
    const int g  = fastp ? gx  : (blk >> 5);     // batches g*2..+2
    const int rg = fastp ? rgx : (blk & 31);     // rows rg*64..+64
    const int b0 = g * 2;

    // ---- one-time: quantize W rows -> LDS int8 (per-row scale), swizzled ----
    // granule G of in-block row r stored at slot G ^ ((r>>3)&7); here r>>3 == w.
#pragma unroll
    for (int rr = 0; rr < 8; ++rr) {
        const int   row = rg * 64 + w * 8 + rr;
        const float4* Wr = (const float4*)(W + (size_t)row * RDIM);
        float m = 0.f;
#pragma unroll
        for (int j = 0; j < 8; ++j) {        // lane covers 8 float4 = 32 elems
            float4 v = Wr[j * 64 + lane];
            m = fmaxf(m, fmaxf(fmaxf(fabsf(v.x), fabsf(v.y)),
                               fmaxf(fabsf(v.z), fabsf(v.w))));
        }
#pragma unroll
        for (int off = 32; off >= 1; off >>= 1)
            m = fmaxf(m, __shfl_xor(m, off, 64));
        const float inv = (m > 0.f) ? 127.f / m : 0.f;
        if (lane == 0) wscale[w * 8 + rr] = (m > 0.f) ? m / 127.f : 0.f;
#pragma unroll
        for (int j = 0; j < 8; ++j) {
            float4 v = Wr[j * 64 + lane];
            const int gsw = (j * 16 + (lane >> 2)) ^ w;          // bits 0-2 XOR
            wlds[(w * 8 + rr) * 512 + gsw * 4 + (lane & 3)] =
                pack4(q8(v.x * inv), q8(v.y * inv), q8(v.z * inv), q8(v.w * inv));
        }
    }

    // ---- hoist Win (loop-invariant per final-thread) ----
    float wn0 = 0.f, wn1 = 0.f, wn2 = 0.f;
    if (tid < 128) {
        const float* wp = Win + (size_t)(rg * 64 + (tid >> 1)) * NIN;
        wn0 = wp[0]; wn1 = wp[1]; wn2 = wp[2];
    }
    __syncthreads();

    unsigned* const ht0 = wsu + HT0_DW;
    unsigned* const ht1 = wsu + HT1_DW;

    // persistent poll regs; bootstrap prefetch (memset zeros = tag0 = h0)
    u32x2 ta = {0, 0}, tb = {0, 0};
    {
        const unsigned* pA0 = ht0 + g * 2048 +        128 * w + 2 * lane;
        const unsigned* pB0 = ht0 + g * 2048 + 1024 + 128 * w + 2 * lane;
        pf_issue_p(ta, tb, pA0, pB0, fastp);
    }
    int dly = 6;                                     // adaptive issue delay (x64cy)

    for (int t = 0; t <= TSTEPS; ++t) {
        unsigned* const hb  = (t & 1) ? ht1 : ht0;   // tags == t live here
        unsigned* const hbn = (t & 1) ? ht0 : ht1;   // t+1 stores go here
        const unsigned tg  = (unsigned)t & 0xffffu;
        const unsigned tg1 = (unsigned)(t + 1) & 0xffffu;
        const int par = t & 1;

        // ---- poll: check-first on prefetched regs; reload only on miss ----
        bool first_hit;
        {
            const unsigned* pA = hb + g * 2048 +        128 * w + 2 * lane;
            const unsigned* pB = hb + g * 2048 + 1024 + 128 * w + 2 * lane;
            asm volatile("s_waitcnt vmcnt(0)" : "+v"(ta), "+v"(tb) :: "memory");
            bool ok = TAGOK(ta, tb, tg);
            first_hit = ok;
            long r = 0;
            while (!ok && r <= POLL_MAX) {           // per-lane; never hangs
                ++r;
                if (r > 1) __builtin_amdgcn_s_sleep(2);
                ld_poll_p(ta, tb, pA, pB, fastp);
                ok = TAGOK(ta, tb, tg);
            }
        }
        // adapt issue delay (wave-uniform: __all -> same update in all lanes)
        dly += __all((int)first_hit) ? -1 : 4;
        dly = dly < 0 ? 0 : (dly > 24 ? 24 : dly);

        // detag: payload dword (4 int8 h values) per batch -> hstage
        const unsigned pdA = (ta[0] & 0xffffu) | (ta[1] << 16);
        const unsigned pdB = (tb[0] & 0xffffu) | (tb[1] << 16);
        hstage[par][0][(w << 6) + lane] = pdA;
        hstage[par][1][(w << 6) + lane] = pdB;

        // ---- x prefetch for the post-barrier final (off the chain) ----
        float xv0 = 0.f, xv1 = 0.f, xv2 = 0.f;
        if (t < TSTEPS && tid < 128) {
            const float* xp = x + ((size_t)(b0 + (tid & 1)) * TSTEPS + t) * NIN;
            xv0 = xp[0]; xv1 = xp[1]; xv2 = xp[2];
        }

        if (t < TSTEPS) {
            // ---- wave-local h window reassembly from hstage (wave-lockstep,
            // compiler inserts the lgkmcnt) — no barrier. Broadcast + 2-way.
            const uint4* hwA = (const uint4*)&hstage[par][0][(w << 6) + (kslot << 3)];
            const uint4* hwB = (const uint4*)&hstage[par][1][(w << 6) + (kslot << 3)];
            const uint4 hA0 = hwA[0], hA1 = hwA[1];
            const uint4 hB0 = hwB[0], hB1 = hwB[1];

            // ---- partial dot: rows [8*rgrp..+8), k [256w+32*kslot..+32)
            int acc[8][2];
#pragma unroll
            for (int rr = 0; rr < 8; ++rr) { acc[rr][0] = 0; acc[rr][1] = 0; }
            const uint4* w4p = (const uint4*)wlds;
            const int g0 = (w << 4) + (((kslot << 1) ^ rgrp) & 15);
#pragma unroll
            for (int rr = 0; rr < 8; ++rr) {
                const int gi = (((rgrp << 3) + rr) << 7);
                uint4 w0 = w4p[gi + g0];
                uint4 w1 = w4p[gi + (g0 ^ 1)];
                acc[rr][0] = dot16(w0, hA0, acc[rr][0]);
                acc[rr][0] = dot16(w1, hA1, acc[rr][0]);
                acc[rr][1] = dot16(w0, hB0, acc[rr][1]);
                acc[rr][1] = dot16(w1, hB1, acc[rr][1]);
            }
            // ---- fold kslot (lane bits 3..5); int add order-exact
#pragma unroll
            for (int rr = 0; rr < 8; ++rr)
#pragma unroll
                for (int b = 0; b < 2; ++b) {
                    int a = acc[rr][b];
                    a += __shfl_xor(a, 8, 64);
                    a += __shfl_xor(a, 16, 64);
                    a += __shfl_xor(a, 32, 64);
                    acc[rr][b] = a;
                }
            if (lane < 8) {                          // lane == rgrp, kslot 0
#pragma unroll
                for (int rr = 0; rr < 8; ++rr) {
                    red[par][w][lane][(rr << 1)]     = acc[rr][0];
                    red[par][w][lane][(rr << 1) + 1] = acc[rr][1];
                }
            }
        }
        __syncthreads();                             // the ONE barrier/step

        // ---- waves 0-1: final 8-way sum, fast tanh, tagged stores ----
        if (t < TSTEPS && tid < 128) {
            const int br = tid >> 1;                 // in-block row 0..63
            const int b  = tid & 1;
            int s = 0;
#pragma unroll
            for (int wp = 0; wp < 8; ++wp)
                s += red[par][wp][br >> 3][((br & 7) << 1) + b];
            float pre = (float)s * wscale[br] * (1.f / 127.f)
                      + wn0 * xv0 + wn1 * xv1 + wn2 * xv2;
            const int qv = q8(fast_tanh(pre) * 127.f);
            // pack rows (2u,2u+1) of batch bb into one tagged dword
            const int qlo = __shfl(qv, ((lane >> 1) << 2) + (lane & 1), 64);
            const int qhi = __shfl(qv, ((lane >> 1) << 2) + 2 + (lane & 1), 64);
            if (lane < 32) {
                const int bb = lane & 1;
                const int u  = (w << 4) + (lane >> 1);   // 0..31 strip dword
                unsigned dv = (unsigned)(qlo & 0xff) |
                              ((unsigned)(qhi & 0xff) << 8) | (tg1 << 16);
                st1_p(hbn + g * 2048 + bb * 1024 + rg * 32 + u, dv, fastp);
            }
        }

        // ---- adaptive-delay cross-step prefetch (after stores) ----
        if (t < TSTEPS) {
            for (int i = 0; i < dly; ++i) __builtin_amdgcn_s_sleep(1);
            const unsigned* nA = hbn + g * 2048 +        128 * w + 2 * lane;
            const unsigned* nB = hbn + g * 2048 + 1024 + 128 * w + 2 * lane;
            pf_issue_p(ta, tb, nA, nB, fastp);
        }

        // ---- waves 2-7: rotating projection (parallel with final/store)
        if (t > 0 && rg == ((t - 1) & 31) && w >= 2) {
            const int pw = w - 2;                    // 0..5
            const int b  = pw / NOUT;                // 0..1
            const int k  = pw % NOUT;                // 0..2
            const float4* wo4 = (const float4*)(Wout + (size_t)k * RDIM);
            float a = 0.f;
#pragma unroll
            for (int j = 0; j < 8; ++j) {
                unsigned hv = hstage[par][b][(lane << 3) + j];
                float4 wf = wo4[(lane << 3) + j];
                a += (float)(int)(signed char)(hv & 0xff)         * wf.x;
                a += (float)(int)(signed char)((hv >> 8) & 0xff)  * wf.y;
                a += (float)(int)(signed char)((hv >> 16) & 0xff) * wf.z;
                a += (float)(int)(signed char)(hv >> 24)          * wf.w;
            }
#pragma unroll
            for (int off = 32; off >= 1; off >>= 1)
                a += __shfl_xor(a, off, 64);
            if (lane == 0)
                out[((size_t)(b0 + b) * TSTEPS + (t - 1)) * NOUT + k] =
                    a * (1.f / 127.f) + bout[k];
        }
        // WAR safety unchanged: parity double-buffering + the per-step
        // barrier order all red/hstage read-write pairs.
    }
}

extern "C" void kernel_launch(void* const* d_in, const int* in_sizes, int n_in,
                              void* d_out, int out_size, void* d_ws, size_t ws_size,
                              hipStream_t stream) {
    const float* x    = (const float*)d_in[0];
    const float* Win  = (const float*)d_in[1];
    const float* W    = (const float*)d_in[2];
    const float* Wout = (const float*)d_in[3];
    const float* bout = (const float*)d_in[4];
    float* out = (float*)d_out;
    unsigned* wsu = (unsigned*)d_ws;

    // zero tagged-h buffers (tag0 + zero payload = valid h0) + discovery/
    // probe/consensus state (~134 KB)
    hipMemsetAsync(d_ws, 0, (size_t)WS_USED_DW * sizeof(unsigned), stream);

    // allow 128 KB dynamic LDS (idempotent; same work every call)
    hipFuncSetAttribute((const void*)esn_persist,
                        hipFuncAttributeMaxDynamicSharedMemorySize, 131072);

    void* args[] = {(void*)&W, (void*)&Win, (void*)&x, (void*)&Wout, (void*)&bout,
                    (void*)&wsu, (void*)&out};
    hipError_t e = hipLaunchCooperativeKernel((const void*)esn_persist,
                                              dim3(NBLK), dim3(NTHR),
                                              args, 131072, stream);
    if (e != hipSuccess) {
        // Fallback: plain launch (256 blocks, 1/CU with ~150KB LDS -> all
        // co-resident; bounded spins guarantee no hang regardless).
        esn_persist<<<dim3(NBLK), dim3(NTHR), 131072, stream>>>(
            W, Win, x, Wout, bout, wsu, out);
    }
}

// Round 13
// 7117.287 us; speedup vs baseline: 1.1142x; 1.1142x over previous
//
#include <hip/hip_runtime.h>
#include <math.h>

// ESN reservoir, persistent kernel, round 31: r27 + capped majority-vote
// adaptation + interleaved two-set fallback polling.
//
// r30 post-mortem (7930us): WRITE_SIZE identical to slow mode (132MB = the
// exchange write-through) => sc0-only stores still write through to EA on
// this chip; the XCD/L2-local-exchange constant does not exist as modeled
// (second falsification after r19). Direction dropped. Reverted to r27.
//
// r27 budget (7360cy/step, VALU ~1920): two attackable serial terms:
//  (a) the adaptive sleep is serial every step and its __all-gated
//      decrement lets ONE laggard lane ratchet dly to the 24 cap = 1536cy;
//  (b) fallback rounds are RT-quantized (~900cy/sample).
//
// r31 changes (poll subsystem only; rest r27-verbatim incl. tanhf):
//  1. dly clamp [0,8] (<=512cy), update -2 on hit / +3 on miss, majority
//     vote (>=56/64 lanes first-hit) instead of __all.
//  2. fallback: ping-pong two sample sets; sleep ~RT/2 OVERLAPS the other
//     set's flight; vmcnt(2) checks the older set => detection granularity
//     ~900 -> ~450cy with no serial sleep. In-flight stragglers drained by
//     a post-barrier vmcnt(0) (free: they land during dot+barrier). Hit
//     results are read only from landed regs (no in-flight reg access).
//
// Protocol unchanged (verified r19/r21/r24-r27): tagged dword = 2x int8 +
// tag16 (= step); dword-store atomicity certifies payload; memset tag0 =
// valid h0. Per-lane single-producer window, k-split waves, W LDS swizzle,
// ONE __syncthreads/step, waves 0-1 final+tanh+tagged stores, waves 2-7
// rotating projection, parity double-buffered red/hstage, bounded spins
// (never hang), int32 dot exact => bit-identical h trajectory.

#define RDIM   2048
#define BATCH  16
#define TSTEPS 2048
#define NIN    3
#define NOUT   3
#define NBLK   256
#define NTHR   512

typedef unsigned u32x2 __attribute__((ext_vector_type(2)));

// workspace layout (dwords)
#define HT0_DW     0            // [8 groups][2 batches][1024] tagged h dwords
#define HT1_DW     16384
#define WS_USED_DW 32768

#define POLL_MAX   (1L << 14)

#define TAGOK(a, b, t) (((a)[0] >> 16) == (t) && ((a)[1] >> 16) == (t) && \
                        ((b)[0] >> 16) == (t) && ((b)[1] >> 16) == (t))

__device__ __forceinline__ void st1_uc(unsigned* p, unsigned v) {
    asm volatile("global_store_dword %0, %1, off sc0 sc1" :: "v"(p), "v"(v) : "memory");
}
// issue one tagged sample set (2x 8B), no wait. "+v": regs stay live/pinned.
__device__ __forceinline__ void pf_issue(u32x2& a, u32x2& b,
                                         const unsigned* pA, const unsigned* pB) {
    asm volatile("global_load_dwordx2 %0, %2, off sc0 sc1\n\t"
                 "global_load_dwordx2 %1, %3, off sc0 sc1"
                 : "+v"(a), "+v"(b) : "v"(pA), "v"(pB) : "memory");
}

__device__ __forceinline__ int q8(float v) {          // round, clamp [-127,127]
    float c = fminf(127.f, fmaxf(-127.f, v));
    return (int)__builtin_rintf(c);
}
__device__ __forceinline__ unsigned pack4(int a, int b, int c, int d) {
    return (a & 0xff) | ((b & 0xff) << 8) | ((c & 0xff) << 16) | ((d & 0xff) << 24);
}
__device__ __forceinline__ int dot4i(unsigned a, unsigned b, int c) {
#if __has_builtin(__builtin_amdgcn_sdot4)
    return __builtin_amdgcn_sdot4((int)a, (int)b, c, false);
#else
    c += (int)(signed char)(a) * (int)(signed char)(b);
    c += (int)(signed char)(a >> 8)  * (int)(signed char)(b >> 8);
    c += (int)(signed char)(a >> 16) * (int)(signed char)(b >> 16);
    c += (int)(signed char)(a >> 24) * (int)(signed char)(b >> 24);
    return c;
#endif
}
__device__ __forceinline__ int dot16(uint4 wq, uint4 hq, int c) {
    c = dot4i(wq.x, hq.x, c);
    c = dot4i(wq.y, hq.y, c);
    c = dot4i(wq.z, hq.z, c);
    c = dot4i(wq.w, hq.w, c);
    return c;
}

extern "C" __global__ void __launch_bounds__(NTHR, 1) esn_persist(
    const float* __restrict__ W,       // [R,R] fp32
    const float* __restrict__ Win,     // [R,3]
    const float* __restrict__ x,       // [B,T,3]
    const float* __restrict__ Wout,    // [3,R]
    const float* __restrict__ bout,    // [3]
    unsigned* wsu,                     // workspace (dwords, see layout)
    float* __restrict__ out)           // [B,T,3]
{
    __shared__ int red[2][8][8][17];               // [par][wave][rgrp][rr*2+b] padded
    __shared__ __align__(16) unsigned hstage[2][2][512];  // [par][batch][payload dw]
    __shared__ float wscale[64];                   // per-row W scale (m/127)
    extern __shared__ unsigned wlds[];             // 128 KB: W int8, swizzled granules

    const int tid  = threadIdx.x;
    const int lane = tid & 63;
    const int w    = tid >> 6;               // wave 0..7
    const int blk  = blockIdx.x;
    const int rg   = blk & 31;               // rows rg*64..+64
    const int g    = blk >> 5;               // batches g*2..+2
    const int b0    = g * 2;
    const int kslot = lane >> 3;             // 0..7: k sub-slice within wave
    const int rgrp  = lane & 7;              // 0..7: row octet within block

    // ---- one-time: quantize W rows -> LDS int8 (per-row scale), swizzled ----
    // granule G of in-block row r stored at slot G ^ ((r>>3)&7); here r>>3 == w.
#pragma unroll
    for (int rr = 0; rr < 8; ++rr) {
        const int   row = rg * 64 + w * 8 + rr;
        const float4* Wr = (const float4*)(W + (size_t)row * RDIM);
        float m = 0.f;
#pragma unroll
        for (int j = 0; j < 8; ++j) {        // lane covers 8 float4 = 32 elems
            float4 v = Wr[j * 64 + lane];
            m = fmaxf(m, fmaxf(fmaxf(fabsf(v.x), fabsf(v.y)),
                               fmaxf(fabsf(v.z), fabsf(v.w))));
        }
#pragma unroll
        for (int off = 32; off >= 1; off >>= 1)
            m = fmaxf(m, __shfl_xor(m, off, 64));
        const float inv = (m > 0.f) ? 127.f / m : 0.f;
        if (lane == 0) wscale[w * 8 + rr] = (m > 0.f) ? m / 127.f : 0.f;
#pragma unroll
        for (int j = 0; j < 8; ++j) {
            float4 v = Wr[j * 64 + lane];
            const int gsw = (j * 16 + (lane >> 2)) ^ w;          // bits 0-2 XOR
            wlds[(w * 8 + rr) * 512 + gsw * 4 + (lane & 3)] =
                pack4(q8(v.x * inv), q8(v.y * inv), q8(v.z * inv), q8(v.w * inv));
        }
    }

    // ---- hoist Win (loop-invariant per final-thread) ----
    float wn0 = 0.f, wn1 = 0.f, wn2 = 0.f;
    if (tid < 128) {
        const float* wp = Win + (size_t)(rg * 64 + (tid >> 1)) * NIN;
        wn0 = wp[0]; wn1 = wp[1]; wn2 = wp[2];
    }
    __syncthreads();

    unsigned* const ht0 = wsu + HT0_DW;
    unsigned* const ht1 = wsu + HT1_DW;

    // poll regs: primary (ta,tb) + fallback ping-pong partner (tc,td);
    // bootstrap prefetch (memset zeros = tag0 = h0)
    u32x2 ta = {0, 0}, tb = {0, 0}, tc = {0, 0}, td = {0, 0};
    {
        const unsigned* pA0 = ht0 + g * 2048 +        128 * w + 2 * lane;
        const unsigned* pB0 = ht0 + g * 2048 + 1024 + 128 * w + 2 * lane;
        pf_issue(ta, tb, pA0, pB0);
    }
    int dly = 4;                                     // adaptive issue delay (x64cy)

    for (int t = 0; t <= TSTEPS; ++t) {
        unsigned* const hb  = (t & 1) ? ht1 : ht0;   // tags == t live here
        unsigned* const hbn = (t & 1) ? ht0 : ht1;   // t+1 stores go here
        const unsigned tg  = (unsigned)t & 0xffffu;
        const unsigned tg1 = (unsigned)(t + 1) & 0xffffu;
        const int par = t & 1;

        // ---- poll: check-first on prefetched regs; interleaved fallback ----
        bool first_hit;
        unsigned rA0, rA1, rB0, rB1;                 // chosen (landed) sample
        {
            const unsigned* pA = hb + g * 2048 +        128 * w + 2 * lane;
            const unsigned* pB = hb + g * 2048 + 1024 + 128 * w + 2 * lane;
            asm volatile("s_waitcnt vmcnt(0)" : "+v"(ta), "+v"(tb) :: "memory");
            first_hit = TAGOK(ta, tb, tg);
            rA0 = ta[0]; rA1 = ta[1]; rB0 = tb[0]; rB1 = tb[1];
            if (!first_hit) {
                bool got = false;
                pf_issue(tc, td, pA, pB);            // immediate retry, in flight
                long r = 0;
                while (!got && r <= POLL_MAX) {      // per-lane; never hangs
                    ++r;
                    __builtin_amdgcn_s_sleep(6);     // ~RT/2, overlaps tc/td flight
                    pf_issue(ta, tb, pA, pB);
                    asm volatile("s_waitcnt vmcnt(2)" : "+v"(tc), "+v"(td) :: "memory");
                    if (TAGOK(tc, td, tg)) {         // tc/td landed; ta/tb fly on
                        rA0 = tc[0]; rA1 = tc[1]; rB0 = td[0]; rB1 = td[1];
                        got = true; break;
                    }
                    ++r;
                    __builtin_amdgcn_s_sleep(6);
                    pf_issue(tc, td, pA, pB);
                    asm volatile("s_waitcnt vmcnt(2)" : "+v"(ta), "+v"(tb) :: "memory");
                    if (TAGOK(ta, tb, tg)) {         // ta/tb landed; tc/td fly on
                        rA0 = ta[0]; rA1 = ta[1]; rB0 = tb[0]; rB1 = tb[1];
                        got = true; break;
                    }
                }
                if (!got) {                          // timeout: drain, take latest
                    asm volatile("s_waitcnt vmcnt(0)"
                                 : "+v"(ta), "+v"(tb), "+v"(tc), "+v"(td) :: "memory");
                    rA0 = ta[0]; rA1 = ta[1]; rB0 = tb[0]; rB1 = tb[1];
                }
            }
        }
        // adapt issue delay: majority vote (one laggard lane can't pin dly)
        {
            int cnt = __popcll(__ballot((int)first_hit));
            dly += (cnt >= 56) ? -2 : 3;
            dly = dly < 0 ? 0 : (dly > 8 ? 8 : dly);
        }

        // detag: payload dword (4 int8 h values) per batch -> hstage
        const unsigned pdA = (rA0 & 0xffffu) | (rA1 << 16);
        const unsigned pdB = (rB0 & 0xffffu) | (rB1 << 16);
        hstage[par][0][(w << 6) + lane] = pdA;
        hstage[par][1][(w << 6) + lane] = pdB;

        // ---- x prefetch for the post-barrier final (off the chain) ----
        float xv0 = 0.f, xv1 = 0.f, xv2 = 0.f;
        if (t < TSTEPS && tid < 128) {
            const float* xp = x + ((size_t)(b0 + (tid & 1)) * TSTEPS + t) * NIN;
            xv0 = xp[0]; xv1 = xp[1]; xv2 = xp[2];
        }

        if (t < TSTEPS) {
            // ---- wave-local h window reassembly from hstage (wave-lockstep,
            // compiler inserts the lgkmcnt) — no barrier. Broadcast + 2-way.
            const uint4* hwA = (const uint4*)&hstage[par][0][(w << 6) + (kslot << 3)];
            const uint4* hwB = (const uint4*)&hstage[par][1][(w << 6) + (kslot << 3)];
            const uint4 hA0 = hwA[0], hA1 = hwA[1];
            const uint4 hB0 = hwB[0], hB1 = hwB[1];

            // ---- partial dot: rows [8*rgrp..+8), k [256w+32*kslot..+32)
            int acc[8][2];
#pragma unroll
            for (int rr = 0; rr < 8; ++rr) { acc[rr][0] = 0; acc[rr][1] = 0; }
            const uint4* w4p = (const uint4*)wlds;
            const int g0 = (w << 4) + (((kslot << 1) ^ rgrp) & 15);
#pragma unroll
            for (int rr = 0; rr < 8; ++rr) {
                const int gi = (((rgrp << 3) + rr) << 7);
                uint4 w0 = w4p[gi + g0];
                uint4 w1 = w4p[gi + (g0 ^ 1)];
                acc[rr][0] = dot16(w0, hA0, acc[rr][0]);
                acc[rr][0] = dot16(w1, hA1, acc[rr][0]);
                acc[rr][1] = dot16(w0, hB0, acc[rr][1]);
                acc[rr][1] = dot16(w1, hB1, acc[rr][1]);
            }
            // ---- fold kslot (lane bits 3..5); int add order-exact
#pragma unroll
            for (int rr = 0; rr < 8; ++rr)
#pragma unroll
                for (int b = 0; b < 2; ++b) {
                    int a = acc[rr][b];
                    a += __shfl_xor(a, 8, 64);
                    a += __shfl_xor(a, 16, 64);
                    a += __shfl_xor(a, 32, 64);
                    acc[rr][b] = a;
                }
            if (lane < 8) {                          // lane == rgrp, kslot 0
#pragma unroll
                for (int rr = 0; rr < 8; ++rr) {
                    red[par][w][lane][(rr << 1)]     = acc[rr][0];
                    red[par][w][lane][(rr << 1) + 1] = acc[rr][1];
                }
            }
        }
        __syncthreads();                             // the ONE barrier/step

        // ---- drain any fallback stragglers (landed long ago: dot+barrier
        // elapsed) so the loop-end reissue can't WAW an in-flight reg.
        if (t < TSTEPS) {
            asm volatile("s_waitcnt vmcnt(0)"
                         : "+v"(ta), "+v"(tb), "+v"(tc), "+v"(td) :: "memory");
        }

        // ---- waves 0-1: final 8-way sum, tanh, tagged stores ----
        if (t < TSTEPS && tid < 128) {
            const int br = tid >> 1;                 // in-block row 0..63
            const int b  = tid & 1;
            int s = 0;
#pragma unroll
            for (int wp = 0; wp < 8; ++wp)
                s += red[par][wp][br >> 3][((br & 7) << 1) + b];
            float pre = (float)s * wscale[br] * (1.f / 127.f)
                      + wn0 * xv0 + wn1 * xv1 + wn2 * xv2;
            const int qv = q8(tanhf(pre) * 127.f);
            // pack rows (2u,2u+1) of batch bb into one tagged dword
            const int qlo = __shfl(qv, ((lane >> 1) << 2) + (lane & 1), 64);
            const int qhi = __shfl(qv, ((lane >> 1) << 2) + 2 + (lane & 1), 64);
            if (lane < 32) {
                const int bb = lane & 1;
                const int u  = (w << 4) + (lane >> 1);   // 0..31 strip dword
                unsigned dv = (unsigned)(qlo & 0xff) |
                              ((unsigned)(qhi & 0xff) << 8) | (tg1 << 16);
                st1_uc(hbn + g * 2048 + bb * 1024 + rg * 32 + u, dv);
            }
        }

        // ---- adaptive-delay cross-step prefetch (after stores) ----
        if (t < TSTEPS) {
            for (int i = 0; i < dly; ++i) __builtin_amdgcn_s_sleep(1);
            const unsigned* nA = hbn + g * 2048 +        128 * w + 2 * lane;
            const unsigned* nB = hbn + g * 2048 + 1024 + 128 * w + 2 * lane;
            pf_issue(ta, tb, nA, nB);
        }

        // ---- waves 2-7: rotating projection (parallel with final/store)
        if (t > 0 && rg == ((t - 1) & 31) && w >= 2) {
            const int pw = w - 2;                    // 0..5
            const int b  = pw / NOUT;                // 0..1
            const int k  = pw % NOUT;                // 0..2
            const float4* wo4 = (const float4*)(Wout + (size_t)k * RDIM);
            float a = 0.f;
#pragma unroll
            for (int j = 0; j < 8; ++j) {
                unsigned hv = hstage[par][b][(lane << 3) + j];
                float4 wf = wo4[(lane << 3) + j];
                a += (float)(int)(signed char)(hv & 0xff)         * wf.x;
                a += (float)(int)(signed char)((hv >> 8) & 0xff)  * wf.y;
                a += (float)(int)(signed char)((hv >> 16) & 0xff) * wf.z;
                a += (float)(int)(signed char)(hv >> 24)          * wf.w;
            }
#pragma unroll
            for (int off = 32; off >= 1; off >>= 1)
                a += __shfl_xor(a, off, 64);
            if (lane == 0)
                out[((size_t)(b0 + b) * TSTEPS + (t - 1)) * NOUT + k] =
                    a * (1.f / 127.f) + bout[k];
        }
        // WAR safety unchanged: parity double-buffering + the per-step
        // barrier order all red/hstage read-write pairs.
    }
}

extern "C" void kernel_launch(void* const* d_in, const int* in_sizes, int n_in,
                              void* d_out, int out_size, void* d_ws, size_t ws_size,
                              hipStream_t stream) {
    const float* x    = (const float*)d_in[0];
    const float* Win  = (const float*)d_in[1];
    const float* W    = (const float*)d_in[2];
    const float* Wout = (const float*)d_in[3];
    const float* bout = (const float*)d_in[4];
    float* out = (float*)d_out;
    unsigned* wsu = (unsigned*)d_ws;

    // zero tagged-h buffers (tag0 + zero payload = valid h0), ~128 KB
    hipMemsetAsync(d_ws, 0, (size_t)WS_USED_DW * sizeof(unsigned), stream);

    // allow 128 KB dynamic LDS (idempotent; same work every call)
    hipFuncSetAttribute((const void*)esn_persist,
                        hipFuncAttributeMaxDynamicSharedMemorySize, 131072);

    void* args[] = {(void*)&W, (void*)&Win, (void*)&x, (void*)&Wout, (void*)&bout,
                    (void*)&wsu, (void*)&out};
    hipError_t e = hipLaunchCooperativeKernel((const void*)esn_persist,
                                              dim3(NBLK), dim3(NTHR),
                                              args, 131072, stream);
    if (e != hipSuccess) {
        // Fallback: plain launch (256 blocks, 1/CU with ~150KB LDS -> all
        // co-resident; bounded spins guarantee no hang regardless).
        esn_persist<<<dim3(NBLK), dim3(NTHR), 131072, stream>>>(
            W, Win, x, Wout, bout, wsu, out);
    }
}

// Round 14
// 6113.590 us; speedup vs baseline: 1.2971x; 1.1642x over previous
//
#include <hip/hip_runtime.h>
#include <math.h>

// ESN reservoir, persistent kernel, round 32: r27 + fused single-load wire
// layout + off-path x prefetch. NO protocol/schedule change.
//
// r31 post-mortem (7117us): capping dly at 8 made samples too early (FETCH
// 557->615MB = more fallback rounds) — r27's adaptive equilibrium correctly
// tracks producer visibility. Five schedule variants (r28-r31) all lose to
// r27; sampling-floor math (sample at T sees T+RT/2; T >= store+250; check
// at T+RT => >=1150cy/step exchange min) says r27 is within ~200-400cy of
// achievable. Barrier-free LDS-atomic finish analyzed and rejected: last
// wave (the slow-producer one) would serialize ~8x tanh+store.
//
// r32 changes (hit path only):
//  1. Fused wire layout T[g][payload d][4] = {A tag-pair, B tag-pair}:
//     poll = ONE global_load_dwordx4 (was 2x dwordx2); wave's poll = 1KB
//     contiguous; fallback cadence tighter.
//  2. x[b,t+1,:] prefetch issued at loop END (h-independent, lands during
//     sleep+RT) — removes 2 global-load issues between poll-hit and dot.
//
// Everything else r27-verbatim: tagged protocol (tag16=step per dword;
// dword-store atomicity certifies payload; memset tag0 = valid h0),
// adaptive post-store prefetch (__all vote, -1/+4, clamp [0,24], init 6),
// immediate-first-retry fallback with s_sleep(2), k-split waves, W LDS
// swizzle, ONE __syncthreads/step, waves 0-1 final+tanhf+tagged stores,
// waves 2-7 rotating projection, parity double-buffered red/hstage,
// bounded spins (never hang), int32 dot exact => bit-identical h.

#define RDIM   2048
#define BATCH  16
#define TSTEPS 2048
#define NIN    3
#define NOUT   3
#define NBLK   256
#define NTHR   512

typedef unsigned u32x4 __attribute__((ext_vector_type(4)));

// workspace layout (dwords)
#define HT0_DW     0            // [8 groups][512 windows][4 tagged dwords]
#define HT1_DW     16384
#define WS_USED_DW 32768

#define POLL_MAX   (1L << 14)

#define TAGOK4(v, t) (((v)[0] >> 16) == (t) && ((v)[1] >> 16) == (t) && \
                      ((v)[2] >> 16) == (t) && ((v)[3] >> 16) == (t))

__device__ __forceinline__ void st1_uc(unsigned* p, unsigned v) {
    asm volatile("global_store_dword %0, %1, off sc0 sc1" :: "v"(p), "v"(v) : "memory");
}
// issue the lane's fused window sample (16B), no wait. "+v": regs pinned.
__device__ __forceinline__ void pf_issue4(u32x4& v, const unsigned* p) {
    asm volatile("global_load_dwordx4 %0, %1, off sc0 sc1"
                 : "+v"(v) : "v"(p) : "memory");
}

__device__ __forceinline__ int q8(float v) {          // round, clamp [-127,127]
    float c = fminf(127.f, fmaxf(-127.f, v));
    return (int)__builtin_rintf(c);
}
__device__ __forceinline__ unsigned pack4(int a, int b, int c, int d) {
    return (a & 0xff) | ((b & 0xff) << 8) | ((c & 0xff) << 16) | ((d & 0xff) << 24);
}
__device__ __forceinline__ int dot4i(unsigned a, unsigned b, int c) {
#if __has_builtin(__builtin_amdgcn_sdot4)
    return __builtin_amdgcn_sdot4((int)a, (int)b, c, false);
#else
    c += (int)(signed char)(a) * (int)(signed char)(b);
    c += (int)(signed char)(a >> 8)  * (int)(signed char)(b >> 8);
    c += (int)(signed char)(a >> 16) * (int)(signed char)(b >> 16);
    c += (int)(signed char)(a >> 24) * (int)(signed char)(b >> 24);
    return c;
#endif
}
__device__ __forceinline__ int dot16(uint4 wq, uint4 hq, int c) {
    c = dot4i(wq.x, hq.x, c);
    c = dot4i(wq.y, hq.y, c);
    c = dot4i(wq.z, hq.z, c);
    c = dot4i(wq.w, hq.w, c);
    return c;
}

extern "C" __global__ void __launch_bounds__(NTHR, 1) esn_persist(
    const float* __restrict__ W,       // [R,R] fp32
    const float* __restrict__ Win,     // [R,3]
    const float* __restrict__ x,       // [B,T,3]
    const float* __restrict__ Wout,    // [3,R]
    const float* __restrict__ bout,    // [3]
    unsigned* wsu,                     // workspace (dwords, see layout)
    float* __restrict__ out)           // [B,T,3]
{
    __shared__ int red[2][8][8][17];               // [par][wave][rgrp][rr*2+b] padded
    __shared__ __align__(16) unsigned hstage[2][2][512];  // [par][batch][payload dw]
    __shared__ float wscale[64];                   // per-row W scale (m/127)
    extern __shared__ unsigned wlds[];             // 128 KB: W int8, swizzled granules

    const int tid  = threadIdx.x;
    const int lane = tid & 63;
    const int w    = tid >> 6;               // wave 0..7
    const int blk  = blockIdx.x;
    const int rg   = blk & 31;               // rows rg*64..+64
    const int g    = blk >> 5;               // batches g*2..+2
    const int b0    = g * 2;
    const int kslot = lane >> 3;             // 0..7: k sub-slice within wave
    const int rgrp  = lane & 7;              // 0..7: row octet within block

    // ---- one-time: quantize W rows -> LDS int8 (per-row scale), swizzled ----
    // granule G of in-block row r stored at slot G ^ ((r>>3)&7); here r>>3 == w.
#pragma unroll
    for (int rr = 0; rr < 8; ++rr) {
        const int   row = rg * 64 + w * 8 + rr;
        const float4* Wr = (const float4*)(W + (size_t)row * RDIM);
        float m = 0.f;
#pragma unroll
        for (int j = 0; j < 8; ++j) {        // lane covers 8 float4 = 32 elems
            float4 v = Wr[j * 64 + lane];
            m = fmaxf(m, fmaxf(fmaxf(fabsf(v.x), fabsf(v.y)),
                               fmaxf(fabsf(v.z), fabsf(v.w))));
        }
#pragma unroll
        for (int off = 32; off >= 1; off >>= 1)
            m = fmaxf(m, __shfl_xor(m, off, 64));
        const float inv = (m > 0.f) ? 127.f / m : 0.f;
        if (lane == 0) wscale[w * 8 + rr] = (m > 0.f) ? m / 127.f : 0.f;
#pragma unroll
        for (int j = 0; j < 8; ++j) {
            float4 v = Wr[j * 64 + lane];
            const int gsw = (j * 16 + (lane >> 2)) ^ w;          // bits 0-2 XOR
            wlds[(w * 8 + rr) * 512 + gsw * 4 + (lane & 3)] =
                pack4(q8(v.x * inv), q8(v.y * inv), q8(v.z * inv), q8(v.w * inv));
        }
    }

    // ---- hoist Win (loop-invariant per final-thread) ----
    float wn0 = 0.f, wn1 = 0.f, wn2 = 0.f;
    if (tid < 128) {
        const float* wp = Win + (size_t)(rg * 64 + (tid >> 1)) * NIN;
        wn0 = wp[0]; wn1 = wp[1]; wn2 = wp[2];
    }
    __syncthreads();

    unsigned* const ht0 = wsu + HT0_DW;
    unsigned* const ht1 = wsu + HT1_DW;

    // lane's fused window address offset: payload dword d = 64w+lane,
    // flat tagged index = d*4  (slots: 0,1 = batch A pair; 2,3 = batch B)
    const int woff = ((w << 6) + lane) << 2;

    // persistent poll reg; bootstrap prefetch (memset zeros = tag0 = h0)
    u32x4 tv = {0, 0, 0, 0};
    pf_issue4(tv, ht0 + g * 2048 + woff);
    // bootstrap x for t=0
    float xv0 = 0.f, xv1 = 0.f, xv2 = 0.f;
    if (tid < 128) {
        const float* xp = x + ((size_t)(b0 + (tid & 1)) * TSTEPS + 0) * NIN;
        xv0 = xp[0]; xv1 = xp[1]; xv2 = xp[2];
    }
    int dly = 6;                                     // adaptive issue delay (x64cy)

    for (int t = 0; t <= TSTEPS; ++t) {
        unsigned* const hb  = (t & 1) ? ht1 : ht0;   // tags == t live here
        unsigned* const hbn = (t & 1) ? ht0 : ht1;   // t+1 stores go here
        const unsigned tg  = (unsigned)t & 0xffffu;
        const unsigned tg1 = (unsigned)(t + 1) & 0xffffu;
        const int par = t & 1;

        // ---- poll: check-first on prefetched reg; reload only on miss ----
        bool first_hit;
        {
            const unsigned* p = hb + g * 2048 + woff;
            asm volatile("s_waitcnt vmcnt(0)" : "+v"(tv) :: "memory");
            bool ok = TAGOK4(tv, tg);
            first_hit = ok;
            long r = 0;
            while (!ok && r <= POLL_MAX) {           // per-lane; never hangs
                ++r;
                if (r > 1) __builtin_amdgcn_s_sleep(2);
                asm volatile("global_load_dwordx4 %0, %1, off sc0 sc1\n\t"
                             "s_waitcnt vmcnt(0)"
                             : "+v"(tv) : "v"(p) : "memory");
                ok = TAGOK4(tv, tg);
            }
        }
        // adapt issue delay (wave-uniform: __all -> same update in all lanes)
        dly += __all((int)first_hit) ? -1 : 4;
        dly = dly < 0 ? 0 : (dly > 24 ? 24 : dly);

        // detag: payload dword (4 int8 h values) per batch -> hstage
        const unsigned pdA = (tv[0] & 0xffffu) | (tv[1] << 16);
        const unsigned pdB = (tv[2] & 0xffffu) | (tv[3] << 16);
        hstage[par][0][(w << 6) + lane] = pdA;
        hstage[par][1][(w << 6) + lane] = pdB;

        if (t < TSTEPS) {
            // ---- wave-local h window reassembly from hstage (wave-lockstep,
            // compiler inserts the lgkmcnt) — no barrier. Broadcast + 2-way.
            const uint4* hwA = (const uint4*)&hstage[par][0][(w << 6) + (kslot << 3)];
            const uint4* hwB = (const uint4*)&hstage[par][1][(w << 6) + (kslot << 3)];
            const uint4 hA0 = hwA[0], hA1 = hwA[1];
            const uint4 hB0 = hwB[0], hB1 = hwB[1];

            // ---- partial dot: rows [8*rgrp..+8), k [256w+32*kslot..+32)
            int acc[8][2];
#pragma unroll
            for (int rr = 0; rr < 8; ++rr) { acc[rr][0] = 0; acc[rr][1] = 0; }
            const uint4* w4p = (const uint4*)wlds;
            const int g0 = (w << 4) + (((kslot << 1) ^ rgrp) & 15);
#pragma unroll
            for (int rr = 0; rr < 8; ++rr) {
                const int gi = (((rgrp << 3) + rr) << 7);
                uint4 w0 = w4p[gi + g0];
                uint4 w1 = w4p[gi + (g0 ^ 1)];
                acc[rr][0] = dot16(w0, hA0, acc[rr][0]);
                acc[rr][0] = dot16(w1, hA1, acc[rr][0]);
                acc[rr][1] = dot16(w0, hB0, acc[rr][1]);
                acc[rr][1] = dot16(w1, hB1, acc[rr][1]);
            }
            // ---- fold kslot (lane bits 3..5); int add order-exact
#pragma unroll
            for (int rr = 0; rr < 8; ++rr)
#pragma unroll
                for (int b = 0; b < 2; ++b) {
                    int a = acc[rr][b];
                    a += __shfl_xor(a, 8, 64);
                    a += __shfl_xor(a, 16, 64);
                    a += __shfl_xor(a, 32, 64);
                    acc[rr][b] = a;
                }
            if (lane < 8) {                          // lane == rgrp, kslot 0
#pragma unroll
                for (int rr = 0; rr < 8; ++rr) {
                    red[par][w][lane][(rr << 1)]     = acc[rr][0];
                    red[par][w][lane][(rr << 1) + 1] = acc[rr][1];
                }
            }
        }
        __syncthreads();                             // the ONE barrier/step

        // ---- waves 0-1: final 8-way sum, tanh, tagged stores ----
        if (t < TSTEPS && tid < 128) {
            const int br = tid >> 1;                 // in-block row 0..63
            const int b  = tid & 1;
            int s = 0;
#pragma unroll
            for (int wp = 0; wp < 8; ++wp)
                s += red[par][wp][br >> 3][((br & 7) << 1) + b];
            float pre = (float)s * wscale[br] * (1.f / 127.f)
                      + wn0 * xv0 + wn1 * xv1 + wn2 * xv2;
            const int qv = q8(tanhf(pre) * 127.f);
            // pack rows (2u,2u+1) of batch bb into one tagged dword at the
            // FUSED address: flat = 64*rg + (u>>1)*4 + (u&1) + 2*bb
            const int qlo = __shfl(qv, ((lane >> 1) << 2) + (lane & 1), 64);
            const int qhi = __shfl(qv, ((lane >> 1) << 2) + 2 + (lane & 1), 64);
            if (lane < 32) {
                const int bb = lane & 1;
                const int u  = (w << 4) + (lane >> 1);   // 0..31 strip dword
                unsigned dv = (unsigned)(qlo & 0xff) |
                              ((unsigned)(qhi & 0xff) << 8) | (tg1 << 16);
                st1_uc(hbn + g * 2048 + 64 * rg + ((u >> 1) << 2)
                           + (u & 1) + (bb << 1), dv);
            }
        }

        // ---- off-path x prefetch for step t+1 (h-independent; lands
        // during the sleep+RT window, consumed post-barrier next iter)
        if (t + 1 < TSTEPS && tid < 128) {
            const float* xp = x + ((size_t)(b0 + (tid & 1)) * TSTEPS + (t + 1)) * NIN;
            xv0 = xp[0]; xv1 = xp[1]; xv2 = xp[2];
        }

        // ---- adaptive-delay cross-step prefetch (after stores) ----
        if (t < TSTEPS) {
            for (int i = 0; i < dly; ++i) __builtin_amdgcn_s_sleep(1);
            pf_issue4(tv, hbn + g * 2048 + woff);
        }

        // ---- waves 2-7: rotating projection (parallel with final/store)
        if (t > 0 && rg == ((t - 1) & 31) && w >= 2) {
            const int pw = w - 2;                    // 0..5
            const int b  = pw / NOUT;                // 0..1
            const int k  = pw % NOUT;                // 0..2
            const float4* wo4 = (const float4*)(Wout + (size_t)k * RDIM);
            float a = 0.f;
#pragma unroll
            for (int j = 0; j < 8; ++j) {
                unsigned hv = hstage[par][b][(lane << 3) + j];
                float4 wf = wo4[(lane << 3) + j];
                a += (float)(int)(signed char)(hv & 0xff)         * wf.x;
                a += (float)(int)(signed char)((hv >> 8) & 0xff)  * wf.y;
                a += (float)(int)(signed char)((hv >> 16) & 0xff) * wf.z;
                a += (float)(int)(signed char)(hv >> 24)          * wf.w;
            }
#pragma unroll
            for (int off = 32; off >= 1; off >>= 1)
                a += __shfl_xor(a, off, 64);
            if (lane == 0)
                out[((size_t)(b0 + b) * TSTEPS + (t - 1)) * NOUT + k] =
                    a * (1.f / 127.f) + bout[k];
        }
        // WAR safety unchanged: parity double-buffering + the per-step
        // barrier order all red/hstage read-write pairs.
    }
}

extern "C" void kernel_launch(void* const* d_in, const int* in_sizes, int n_in,
                              void* d_out, int out_size, void* d_ws, size_t ws_size,
                              hipStream_t stream) {
    const float* x    = (const float*)d_in[0];
    const float* Win  = (const float*)d_in[1];
    const float* W    = (const float*)d_in[2];
    const float* Wout = (const float*)d_in[3];
    const float* bout = (const float*)d_in[4];
    float* out = (float*)d_out;
    unsigned* wsu = (unsigned*)d_ws;

    // zero tagged-h buffers (tag0 + zero payload = valid h0), ~128 KB
    hipMemsetAsync(d_ws, 0, (size_t)WS_USED_DW * sizeof(unsigned), stream);

    // allow 128 KB dynamic LDS (idempotent; same work every call)
    hipFuncSetAttribute((const void*)esn_persist,
                        hipFuncAttributeMaxDynamicSharedMemorySize, 131072);

    void* args[] = {(void*)&W, (void*)&Win, (void*)&x, (void*)&Wout, (void*)&bout,
                    (void*)&wsu, (void*)&out};
    hipError_t e = hipLaunchCooperativeKernel((const void*)esn_persist,
                                              dim3(NBLK), dim3(NTHR),
                                              args, 131072, stream);
    if (e != hipSuccess) {
        // Fallback: plain launch (256 blocks, 1/CU with ~150KB LDS -> all
        // co-resident; bounded spins guarantee no hang regardless).
        esn_persist<<<dim3(NBLK), dim3(NTHR), 131072, stream>>>(
            W, Win, x, Wout, bout, wsu, out);
    }
}

// Round 16
// 5406.157 us; speedup vs baseline: 1.4668x; 1.1309x over previous
//
#include <hip/hip_runtime.h>
#include <math.h>

// ESN reservoir, persistent kernel, round 34 = r33 RESUBMIT (r33 died to an
// infra container failure — same signature as r26, which passed unchanged
// on resubmit; no kernel verdict was issued). Source identical to r33.
//
// r33 design (untested, predictions stand):
//  1. W slices in registers: prologue pass1 -> wscale/winv in LDS; pass2:
//     each thread loads rows 8*rgrp+rr, k [256w+32kslot,+32) from global
//     (L3-hot, one-time), quantizes inline (identical math -> bit-identical
//     h), packs wr0[8]/wr1[8] uint4 regs (static unrolled indexing; ~130
//     VGPR total, 8 waves/CU preserved). Dot = pure register sdot4; W LDS
//     reads + swizzle addressing + lgkmcnt leave the critical path.
//  2. Launch still passes 131072 dynamic LDS (unused) to pin 1 block/CU.
//  3. Projection r21-stride (r=j*64+lane scalar reads): kills its 16-way
//     bank conflict.
//
// Everything else r32-verbatim: fused dwordx4 wire (tag16=step per dword;
// dword-store atomicity certifies payload; memset tag0 = valid h0),
// adaptive post-store prefetch (-1/+4 clamp [0,24]), per-lane poll with
// bounded spins (never hang), k-split waves, ONE __syncthreads/step,
// waves 0-1 final+tanhf+tagged stores, waves 2-7 rotating projection,
// parity double-buffered red/hstage, off-path x prefetch, int32 dot exact.

#define RDIM   2048
#define BATCH  16
#define TSTEPS 2048
#define NIN    3
#define NOUT   3
#define NBLK   256
#define NTHR   512

typedef unsigned u32x4 __attribute__((ext_vector_type(4)));

// workspace layout (dwords)
#define HT0_DW     0            // [8 groups][512 windows][4 tagged dwords]
#define HT1_DW     16384
#define WS_USED_DW 32768

#define POLL_MAX   (1L << 14)

#define TAGOK4(v, t) (((v)[0] >> 16) == (t) && ((v)[1] >> 16) == (t) && \
                      ((v)[2] >> 16) == (t) && ((v)[3] >> 16) == (t))

__device__ __forceinline__ void st1_uc(unsigned* p, unsigned v) {
    asm volatile("global_store_dword %0, %1, off sc0 sc1" :: "v"(p), "v"(v) : "memory");
}
// issue the lane's fused window sample (16B), no wait. "+v": regs pinned.
__device__ __forceinline__ void pf_issue4(u32x4& v, const unsigned* p) {
    asm volatile("global_load_dwordx4 %0, %1, off sc0 sc1"
                 : "+v"(v) : "v"(p) : "memory");
}

__device__ __forceinline__ int q8(float v) {          // round, clamp [-127,127]
    float c = fminf(127.f, fmaxf(-127.f, v));
    return (int)__builtin_rintf(c);
}
__device__ __forceinline__ unsigned pack4(int a, int b, int c, int d) {
    return (a & 0xff) | ((b & 0xff) << 8) | ((c & 0xff) << 16) | ((d & 0xff) << 24);
}
__device__ __forceinline__ unsigned qpack(float4 v, float inv) {
    return pack4(q8(v.x * inv), q8(v.y * inv), q8(v.z * inv), q8(v.w * inv));
}
__device__ __forceinline__ int dot4i(unsigned a, unsigned b, int c) {
#if __has_builtin(__builtin_amdgcn_sdot4)
    return __builtin_amdgcn_sdot4((int)a, (int)b, c, false);
#else
    c += (int)(signed char)(a) * (int)(signed char)(b);
    c += (int)(signed char)(a >> 8)  * (int)(signed char)(b >> 8);
    c += (int)(signed char)(a >> 16) * (int)(signed char)(b >> 16);
    c += (int)(signed char)(a >> 24) * (int)(signed char)(b >> 24);
    return c;
#endif
}
__device__ __forceinline__ int dot16(uint4 wq, uint4 hq, int c) {
    c = dot4i(wq.x, hq.x, c);
    c = dot4i(wq.y, hq.y, c);
    c = dot4i(wq.z, hq.z, c);
    c = dot4i(wq.w, hq.w, c);
    return c;
}

extern "C" __global__ void __launch_bounds__(NTHR, 1) esn_persist(
    const float* __restrict__ W,       // [R,R] fp32
    const float* __restrict__ Win,     // [R,3]
    const float* __restrict__ x,       // [B,T,3]
    const float* __restrict__ Wout,    // [3,R]
    const float* __restrict__ bout,    // [3]
    unsigned* wsu,                     // workspace (dwords, see layout)
    float* __restrict__ out)           // [B,T,3]
{
    __shared__ int red[2][8][8][17];               // [par][wave][rgrp][rr*2+b] padded
    __shared__ __align__(16) unsigned hstage[2][2][512];  // [par][batch][payload dw]
    __shared__ float wscale[64];                   // per-row W scale (m/127)
    __shared__ float winv[64];                     // per-row 127/m
    extern __shared__ unsigned wlds[];             // unused; launch still passes
                                                   // 131072 to pin 1 block/CU
    (void)wlds;

    const int tid  = threadIdx.x;
    const int lane = tid & 63;
    const int w    = tid >> 6;               // wave 0..7
    const int blk  = blockIdx.x;
    const int rg   = blk & 31;               // rows rg*64..+64
    const int g    = blk >> 5;               // batches g*2..+2
    const int b0    = g * 2;
    const int kslot = lane >> 3;             // 0..7: k sub-slice within wave
    const int rgrp  = lane & 7;              // 0..7: row octet within block

    // ---- prologue pass 1: per-row absmax -> wscale, winv (wave w owns
    // rows rg*64 + 8w .. +8; lane covers 8 float4 = 32 elems of the row)
#pragma unroll
    for (int rr = 0; rr < 8; ++rr) {
        const int   row = rg * 64 + w * 8 + rr;
        const float4* Wr = (const float4*)(W + (size_t)row * RDIM);
        float m = 0.f;
#pragma unroll
        for (int j = 0; j < 8; ++j) {
            float4 v = Wr[j * 64 + lane];
            m = fmaxf(m, fmaxf(fmaxf(fabsf(v.x), fabsf(v.y)),
                               fmaxf(fabsf(v.z), fabsf(v.w))));
        }
#pragma unroll
        for (int off = 32; off >= 1; off >>= 1)
            m = fmaxf(m, __shfl_xor(m, off, 64));
        if (lane == 0) {
            wscale[w * 8 + rr] = (m > 0.f) ? m / 127.f : 0.f;
            winv[w * 8 + rr]   = (m > 0.f) ? 127.f / m : 0.f;
        }
    }
    __syncthreads();

    // ---- prologue pass 2: load THIS thread's W slice into registers.
    // Thread (w,kslot,rgrp): rows 8*rgrp+rr, k in [256w+32kslot, +32).
    // One-time global read (L3-hot after pass 1). Identical quantization
    // math (q8(v*inv)) => bit-identical h trajectory.
    uint4 wr0[8], wr1[8];
#pragma unroll
    for (int rr = 0; rr < 8; ++rr) {
        const int row = rg * 64 + 8 * rgrp + rr;
        const float inv = winv[8 * rgrp + rr];
        const float4* Wr = (const float4*)(W + (size_t)row * RDIM
                                             + 256 * w + 32 * kslot);
        float4 a0 = Wr[0], a1 = Wr[1], a2 = Wr[2], a3 = Wr[3];
        float4 a4 = Wr[4], a5 = Wr[5], a6 = Wr[6], a7 = Wr[7];
        wr0[rr] = make_uint4(qpack(a0, inv), qpack(a1, inv),
                             qpack(a2, inv), qpack(a3, inv));
        wr1[rr] = make_uint4(qpack(a4, inv), qpack(a5, inv),
                             qpack(a6, inv), qpack(a7, inv));
    }

    // ---- hoist Win (loop-invariant per final-thread) ----
    float wn0 = 0.f, wn1 = 0.f, wn2 = 0.f;
    if (tid < 128) {
        const float* wp = Win + (size_t)(rg * 64 + (tid >> 1)) * NIN;
        wn0 = wp[0]; wn1 = wp[1]; wn2 = wp[2];
    }

    unsigned* const ht0 = wsu + HT0_DW;
    unsigned* const ht1 = wsu + HT1_DW;

    // lane's fused window address offset: payload dword d = 64w+lane,
    // flat tagged index = d*4  (slots: 0,1 = batch A pair; 2,3 = batch B)
    const int woff = ((w << 6) + lane) << 2;

    // persistent poll reg; bootstrap prefetch (memset zeros = tag0 = h0)
    u32x4 tv = {0, 0, 0, 0};
    pf_issue4(tv, ht0 + g * 2048 + woff);
    // bootstrap x for t=0
    float xv0 = 0.f, xv1 = 0.f, xv2 = 0.f;
    if (tid < 128) {
        const float* xp = x + ((size_t)(b0 + (tid & 1)) * TSTEPS + 0) * NIN;
        xv0 = xp[0]; xv1 = xp[1]; xv2 = xp[2];
    }
    int dly = 6;                                     // adaptive issue delay (x64cy)

    for (int t = 0; t <= TSTEPS; ++t) {
        unsigned* const hb  = (t & 1) ? ht1 : ht0;   // tags == t live here
        unsigned* const hbn = (t & 1) ? ht0 : ht1;   // t+1 stores go here
        const unsigned tg  = (unsigned)t & 0xffffu;
        const unsigned tg1 = (unsigned)(t + 1) & 0xffffu;
        const int par = t & 1;

        // ---- poll: check-first on prefetched reg; reload only on miss ----
        bool first_hit;
        {
            const unsigned* p = hb + g * 2048 + woff;
            asm volatile("s_waitcnt vmcnt(0)" : "+v"(tv) :: "memory");
            bool ok = TAGOK4(tv, tg);
            first_hit = ok;
            long r = 0;
            while (!ok && r <= POLL_MAX) {           // per-lane; never hangs
                ++r;
                if (r > 1) __builtin_amdgcn_s_sleep(2);
                asm volatile("global_load_dwordx4 %0, %1, off sc0 sc1\n\t"
                             "s_waitcnt vmcnt(0)"
                             : "+v"(tv) : "v"(p) : "memory");
                ok = TAGOK4(tv, tg);
            }
        }
        // adapt issue delay (wave-uniform: __all -> same update in all lanes)
        dly += __all((int)first_hit) ? -1 : 4;
        dly = dly < 0 ? 0 : (dly > 24 ? 24 : dly);

        // detag: payload dword (4 int8 h values) per batch -> hstage
        const unsigned pdA = (tv[0] & 0xffffu) | (tv[1] << 16);
        const unsigned pdB = (tv[2] & 0xffffu) | (tv[3] << 16);
        hstage[par][0][(w << 6) + lane] = pdA;
        hstage[par][1][(w << 6) + lane] = pdB;

        if (t < TSTEPS) {
            // ---- wave-local h window reassembly from hstage (wave-lockstep,
            // compiler inserts the lgkmcnt) — no barrier. Broadcast + 2-way.
            const uint4* hwA = (const uint4*)&hstage[par][0][(w << 6) + (kslot << 3)];
            const uint4* hwB = (const uint4*)&hstage[par][1][(w << 6) + (kslot << 3)];
            const uint4 hA0 = hwA[0], hA1 = hwA[1];
            const uint4 hB0 = hwB[0], hB1 = hwB[1];

            // ---- partial dot from REGISTERS: rows [8*rgrp..+8),
            // k [256w+32*kslot..+32). Pure sdot4, no LDS on this path.
            int acc[8][2];
#pragma unroll
            for (int rr = 0; rr < 8; ++rr) {
                int a0 = dot16(wr0[rr], hA0, 0);
                a0     = dot16(wr1[rr], hA1, a0);
                int a1 = dot16(wr0[rr], hB0, 0);
                a1     = dot16(wr1[rr], hB1, a1);
                acc[rr][0] = a0;
                acc[rr][1] = a1;
            }
            // ---- fold kslot (lane bits 3..5); int add order-exact
#pragma unroll
            for (int rr = 0; rr < 8; ++rr)
#pragma unroll
                for (int b = 0; b < 2; ++b) {
                    int a = acc[rr][b];
                    a += __shfl_xor(a, 8, 64);
                    a += __shfl_xor(a, 16, 64);
                    a += __shfl_xor(a, 32, 64);
                    acc[rr][b] = a;
                }
            if (lane < 8) {                          // lane == rgrp, kslot 0
#pragma unroll
                for (int rr = 0; rr < 8; ++rr) {
                    red[par][w][lane][(rr << 1)]     = acc[rr][0];
                    red[par][w][lane][(rr << 1) + 1] = acc[rr][1];
                }
            }
        }
        __syncthreads();                             // the ONE barrier/step

        // ---- waves 0-1: final 8-way sum, tanh, tagged stores ----
        if (t < TSTEPS && tid < 128) {
            const int br = tid >> 1;                 // in-block row 0..63
            const int b  = tid & 1;
            int s = 0;
#pragma unroll
            for (int wp = 0; wp < 8; ++wp)
                s += red[par][wp][br >> 3][((br & 7) << 1) + b];
            float pre = (float)s * wscale[br] * (1.f / 127.f)
                      + wn0 * xv0 + wn1 * xv1 + wn2 * xv2;
            const int qv = q8(tanhf(pre) * 127.f);
            // pack rows (2u,2u+1) of batch bb into one tagged dword at the
            // FUSED address: flat = 64*rg + (u>>1)*4 + (u&1) + 2*bb
            const int qlo = __shfl(qv, ((lane >> 1) << 2) + (lane & 1), 64);
            const int qhi = __shfl(qv, ((lane >> 1) << 2) + 2 + (lane & 1), 64);
            if (lane < 32) {
                const int bb = lane & 1;
                const int u  = (w << 4) + (lane >> 1);   // 0..31 strip dword
                unsigned dv = (unsigned)(qlo & 0xff) |
                              ((unsigned)(qhi & 0xff) << 8) | (tg1 << 16);
                st1_uc(hbn + g * 2048 + 64 * rg + ((u >> 1) << 2)
                           + (u & 1) + (bb << 1), dv);
            }
        }

        // ---- off-path x prefetch for step t+1 (h-independent; lands
        // during the sleep+RT window, consumed post-barrier next iter)
        if (t + 1 < TSTEPS && tid < 128) {
            const float* xp = x + ((size_t)(b0 + (tid & 1)) * TSTEPS + (t + 1)) * NIN;
            xv0 = xp[0]; xv1 = xp[1]; xv2 = xp[2];
        }

        // ---- adaptive-delay cross-step prefetch (after stores) ----
        if (t < TSTEPS) {
            for (int i = 0; i < dly; ++i) __builtin_amdgcn_s_sleep(1);
            pf_issue4(tv, hbn + g * 2048 + woff);
        }

        // ---- waves 2-7: rotating projection (parallel with final/store).
        // r21-stride (r = j*64+lane): conflict-free scalar LDS reads,
        // coalesced Wout reads.
        if (t > 0 && rg == ((t - 1) & 31) && w >= 2) {
            const int pw = w - 2;                    // 0..5
            const int b  = pw / NOUT;                // 0..1
            const int k  = pw % NOUT;                // 0..2
            const signed char* hsv = (const signed char*)hstage[par][b];
            float a = 0.f;
#pragma unroll
            for (int j = 0; j < 32; ++j) {
                const int r = j * 64 + lane;
                a += (float)hsv[r] * Wout[k * RDIM + r];
            }
#pragma unroll
            for (int off = 32; off >= 1; off >>= 1)
                a += __shfl_xor(a, off, 64);
            if (lane == 0)
                out[((size_t)(b0 + b) * TSTEPS + (t - 1)) * NOUT + k] =
                    a * (1.f / 127.f) + bout[k];
        }
        // WAR safety unchanged: parity double-buffering + the per-step
        // barrier order all red/hstage read-write pairs.
    }
}

extern "C" void kernel_launch(void* const* d_in, const int* in_sizes, int n_in,
                              void* d_out, int out_size, void* d_ws, size_t ws_size,
                              hipStream_t stream) {
    const float* x    = (const float*)d_in[0];
    const float* Win  = (const float*)d_in[1];
    const float* W    = (const float*)d_in[2];
    const float* Wout = (const float*)d_in[3];
    const float* bout = (const float*)d_in[4];
    float* out = (float*)d_out;
    unsigned* wsu = (unsigned*)d_ws;

    // zero tagged-h buffers (tag0 + zero payload = valid h0), ~128 KB
    hipMemsetAsync(d_ws, 0, (size_t)WS_USED_DW * sizeof(unsigned), stream);

    // allow + allocate 128 KB dynamic LDS: UNUSED by the kernel, kept to
    // pin occupancy at 1 block/CU (without it 2 blocks could share a CU,
    // breaking the latency symmetry the exchange tuning relies on).
    hipFuncSetAttribute((const void*)esn_persist,
                        hipFuncAttributeMaxDynamicSharedMemorySize, 131072);

    void* args[] = {(void*)&W, (void*)&Win, (void*)&x, (void*)&Wout, (void*)&bout,
                    (void*)&wsu, (void*)&out};
    hipError_t e = hipLaunchCooperativeKernel((const void*)esn_persist,
                                              dim3(NBLK), dim3(NTHR),
                                              args, 131072, stream);
    if (e != hipSuccess) {
        // Fallback: plain launch (256 blocks, 1/CU with ~150KB LDS -> all
        // co-resident; bounded spins guarantee no hang regardless).
        esn_persist<<<dim3(NBLK), dim3(NTHR), 131072, stream>>>(
            W, Win, x, Wout, bout, wsu, out);
    }
}

// Round 17
// 5311.526 us; speedup vs baseline: 1.4930x; 1.0178x over previous
//
#include <hip/hip_runtime.h>
#include <math.h>

// ESN reservoir, persistent kernel, round 35: r34 + fast tanh (only change).
//
// r34 post-mortem (5406us, best, -11.6%): W-in-VGPRs verified — bank
// conflicts 2.9e8 -> 2.1e7 (14x), VALUBusy 29.5%, VGPR 128. Remaining step
// (6330cy) ~70% exchange limit-cycle (store-visible ~700, sleep+RT detect
// ~1300-1800, jitter tail) which r28-r31 showed can't be re-scheduled away,
// plus ~600cy post-barrier finish.
//
// r35: replace libm tanhf (~80-150cy, branchy) on the barrier->store path
// with tanh(x) = 1 - 2*rcp(e^{2x}+1), x127 folded into one fma
// (127 - 254*rcp). EVIDENCE: r29 and r30 both carried this exact formula
// and both measured absmax bit-identical 0.0078125 on this data (their
// regressions had separately-identified structural causes). Endpoints:
// x->+inf: e2=inf, rcp=0 -> 127 ✓; x->-inf: e2=0, rcp(1)=1 -> -127 ✓.
//
// Everything else r34-verbatim: W slices in VGPRs (wr0/wr1, static
// unrolled), fused dwordx4 wire (tag16=step per dword; dword-store
// atomicity certifies payload; memset tag0 = valid h0), adaptive
// post-store prefetch (-1/+4 clamp [0,24]), per-lane poll with bounded
// spins (never hang), k-split waves, ONE __syncthreads/step, waves 0-1
// final+tagged stores, waves 2-7 rotating projection (r21-stride),
// parity double-buffered red/hstage, off-path x prefetch, unused 128KB
// dynamic LDS pins 1 block/CU, int32 dot exact.

#define RDIM   2048
#define BATCH  16
#define TSTEPS 2048
#define NIN    3
#define NOUT   3
#define NBLK   256
#define NTHR   512

typedef unsigned u32x4 __attribute__((ext_vector_type(4)));

// workspace layout (dwords)
#define HT0_DW     0            // [8 groups][512 windows][4 tagged dwords]
#define HT1_DW     16384
#define WS_USED_DW 32768

#define POLL_MAX   (1L << 14)

#define TAGOK4(v, t) (((v)[0] >> 16) == (t) && ((v)[1] >> 16) == (t) && \
                      ((v)[2] >> 16) == (t) && ((v)[3] >> 16) == (t))

__device__ __forceinline__ void st1_uc(unsigned* p, unsigned v) {
    asm volatile("global_store_dword %0, %1, off sc0 sc1" :: "v"(p), "v"(v) : "memory");
}
// issue the lane's fused window sample (16B), no wait. "+v": regs pinned.
__device__ __forceinline__ void pf_issue4(u32x4& v, const unsigned* p) {
    asm volatile("global_load_dwordx4 %0, %1, off sc0 sc1"
                 : "+v"(v) : "v"(p) : "memory");
}

__device__ __forceinline__ int q8(float v) {          // round, clamp [-127,127]
    float c = fminf(127.f, fmaxf(-127.f, v));
    return (int)__builtin_rintf(c);
}
// q8(tanh(x)*127) with tanh = 1 - 2/(e^{2x}+1); x127 folded: 127 - 254*rcp.
__device__ __forceinline__ int q8_tanh127(float x) {
    float e2 = __expf(2.f * x);
    float v  = fmaf(-254.f, __builtin_amdgcn_rcpf(e2 + 1.f), 127.f);
    return (int)__builtin_rintf(fminf(127.f, fmaxf(-127.f, v)));
}
__device__ __forceinline__ unsigned pack4(int a, int b, int c, int d) {
    return (a & 0xff) | ((b & 0xff) << 8) | ((c & 0xff) << 16) | ((d & 0xff) << 24);
}
__device__ __forceinline__ unsigned qpack(float4 v, float inv) {
    return pack4(q8(v.x * inv), q8(v.y * inv), q8(v.z * inv), q8(v.w * inv));
}
__device__ __forceinline__ int dot4i(unsigned a, unsigned b, int c) {
#if __has_builtin(__builtin_amdgcn_sdot4)
    return __builtin_amdgcn_sdot4((int)a, (int)b, c, false);
#else
    c += (int)(signed char)(a) * (int)(signed char)(b);
    c += (int)(signed char)(a >> 8)  * (int)(signed char)(b >> 8);
    c += (int)(signed char)(a >> 16) * (int)(signed char)(b >> 16);
    c += (int)(signed char)(a >> 24) * (int)(signed char)(b >> 24);
    return c;
#endif
}
__device__ __forceinline__ int dot16(uint4 wq, uint4 hq, int c) {
    c = dot4i(wq.x, hq.x, c);
    c = dot4i(wq.y, hq.y, c);
    c = dot4i(wq.z, hq.z, c);
    c = dot4i(wq.w, hq.w, c);
    return c;
}

extern "C" __global__ void __launch_bounds__(NTHR, 1) esn_persist(
    const float* __restrict__ W,       // [R,R] fp32
    const float* __restrict__ Win,     // [R,3]
    const float* __restrict__ x,       // [B,T,3]
    const float* __restrict__ Wout,    // [3,R]
    const float* __restrict__ bout,    // [3]
    unsigned* wsu,                     // workspace (dwords, see layout)
    float* __restrict__ out)           // [B,T,3]
{
    __shared__ int red[2][8][8][17];               // [par][wave][rgrp][rr*2+b] padded
    __shared__ __align__(16) unsigned hstage[2][2][512];  // [par][batch][payload dw]
    __shared__ float wscale[64];                   // per-row W scale (m/127)
    __shared__ float winv[64];                     // per-row 127/m
    extern __shared__ unsigned wlds[];             // unused; launch still passes
                                                   // 131072 to pin 1 block/CU
    (void)wlds;

    const int tid  = threadIdx.x;
    const int lane = tid & 63;
    const int w    = tid >> 6;               // wave 0..7
    const int blk  = blockIdx.x;
    const int rg   = blk & 31;               // rows rg*64..+64
    const int g    = blk >> 5;               // batches g*2..+2
    const int b0    = g * 2;
    const int kslot = lane >> 3;             // 0..7: k sub-slice within wave
    const int rgrp  = lane & 7;              // 0..7: row octet within block

    // ---- prologue pass 1: per-row absmax -> wscale, winv (wave w owns
    // rows rg*64 + 8w .. +8; lane covers 8 float4 = 32 elems of the row)
#pragma unroll
    for (int rr = 0; rr < 8; ++rr) {
        const int   row = rg * 64 + w * 8 + rr;
        const float4* Wr = (const float4*)(W + (size_t)row * RDIM);
        float m = 0.f;
#pragma unroll
        for (int j = 0; j < 8; ++j) {
            float4 v = Wr[j * 64 + lane];
            m = fmaxf(m, fmaxf(fmaxf(fabsf(v.x), fabsf(v.y)),
                               fmaxf(fabsf(v.z), fabsf(v.w))));
        }
#pragma unroll
        for (int off = 32; off >= 1; off >>= 1)
            m = fmaxf(m, __shfl_xor(m, off, 64));
        if (lane == 0) {
            wscale[w * 8 + rr] = (m > 0.f) ? m / 127.f : 0.f;
            winv[w * 8 + rr]   = (m > 0.f) ? 127.f / m : 0.f;
        }
    }
    __syncthreads();

    // ---- prologue pass 2: load THIS thread's W slice into registers.
    // Thread (w,kslot,rgrp): rows 8*rgrp+rr, k in [256w+32kslot, +32).
    // One-time global read (L3-hot after pass 1). Identical quantization
    // math (q8(v*inv)) => bit-identical h trajectory.
    uint4 wr0[8], wr1[8];
#pragma unroll
    for (int rr = 0; rr < 8; ++rr) {
        const int row = rg * 64 + 8 * rgrp + rr;
        const float inv = winv[8 * rgrp + rr];
        const float4* Wr = (const float4*)(W + (size_t)row * RDIM
                                             + 256 * w + 32 * kslot);
        float4 a0 = Wr[0], a1 = Wr[1], a2 = Wr[2], a3 = Wr[3];
        float4 a4 = Wr[4], a5 = Wr[5], a6 = Wr[6], a7 = Wr[7];
        wr0[rr] = make_uint4(qpack(a0, inv), qpack(a1, inv),
                             qpack(a2, inv), qpack(a3, inv));
        wr1[rr] = make_uint4(qpack(a4, inv), qpack(a5, inv),
                             qpack(a6, inv), qpack(a7, inv));
    }

    // ---- hoist Win (loop-invariant per final-thread) ----
    float wn0 = 0.f, wn1 = 0.f, wn2 = 0.f;
    if (tid < 128) {
        const float* wp = Win + (size_t)(rg * 64 + (tid >> 1)) * NIN;
        wn0 = wp[0]; wn1 = wp[1]; wn2 = wp[2];
    }

    unsigned* const ht0 = wsu + HT0_DW;
    unsigned* const ht1 = wsu + HT1_DW;

    // lane's fused window address offset: payload dword d = 64w+lane,
    // flat tagged index = d*4  (slots: 0,1 = batch A pair; 2,3 = batch B)
    const int woff = ((w << 6) + lane) << 2;

    // persistent poll reg; bootstrap prefetch (memset zeros = tag0 = h0)
    u32x4 tv = {0, 0, 0, 0};
    pf_issue4(tv, ht0 + g * 2048 + woff);
    // bootstrap x for t=0
    float xv0 = 0.f, xv1 = 0.f, xv2 = 0.f;
    if (tid < 128) {
        const float* xp = x + ((size_t)(b0 + (tid & 1)) * TSTEPS + 0) * NIN;
        xv0 = xp[0]; xv1 = xp[1]; xv2 = xp[2];
    }
    int dly = 6;                                     // adaptive issue delay (x64cy)

    for (int t = 0; t <= TSTEPS; ++t) {
        unsigned* const hb  = (t & 1) ? ht1 : ht0;   // tags == t live here
        unsigned* const hbn = (t & 1) ? ht0 : ht1;   // t+1 stores go here
        const unsigned tg  = (unsigned)t & 0xffffu;
        const unsigned tg1 = (unsigned)(t + 1) & 0xffffu;
        const int par = t & 1;

        // ---- poll: check-first on prefetched reg; reload only on miss ----
        bool first_hit;
        {
            const unsigned* p = hb + g * 2048 + woff;
            asm volatile("s_waitcnt vmcnt(0)" : "+v"(tv) :: "memory");
            bool ok = TAGOK4(tv, tg);
            first_hit = ok;
            long r = 0;
            while (!ok && r <= POLL_MAX) {           // per-lane; never hangs
                ++r;
                if (r > 1) __builtin_amdgcn_s_sleep(2);
                asm volatile("global_load_dwordx4 %0, %1, off sc0 sc1\n\t"
                             "s_waitcnt vmcnt(0)"
                             : "+v"(tv) : "v"(p) : "memory");
                ok = TAGOK4(tv, tg);
            }
        }
        // adapt issue delay (wave-uniform: __all -> same update in all lanes)
        dly += __all((int)first_hit) ? -1 : 4;
        dly = dly < 0 ? 0 : (dly > 24 ? 24 : dly);

        // detag: payload dword (4 int8 h values) per batch -> hstage
        const unsigned pdA = (tv[0] & 0xffffu) | (tv[1] << 16);
        const unsigned pdB = (tv[2] & 0xffffu) | (tv[3] << 16);
        hstage[par][0][(w << 6) + lane] = pdA;
        hstage[par][1][(w << 6) + lane] = pdB;

        if (t < TSTEPS) {
            // ---- wave-local h window reassembly from hstage (wave-lockstep,
            // compiler inserts the lgkmcnt) — no barrier. Broadcast + 2-way.
            const uint4* hwA = (const uint4*)&hstage[par][0][(w << 6) + (kslot << 3)];
            const uint4* hwB = (const uint4*)&hstage[par][1][(w << 6) + (kslot << 3)];
            const uint4 hA0 = hwA[0], hA1 = hwA[1];
            const uint4 hB0 = hwB[0], hB1 = hwB[1];

            // ---- partial dot from REGISTERS: rows [8*rgrp..+8),
            // k [256w+32*kslot..+32). Pure sdot4, no LDS on this path.
            int acc[8][2];
#pragma unroll
            for (int rr = 0; rr < 8; ++rr) {
                int a0 = dot16(wr0[rr], hA0, 0);
                a0     = dot16(wr1[rr], hA1, a0);
                int a1 = dot16(wr0[rr], hB0, 0);
                a1     = dot16(wr1[rr], hB1, a1);
                acc[rr][0] = a0;
                acc[rr][1] = a1;
            }
            // ---- fold kslot (lane bits 3..5); int add order-exact
#pragma unroll
            for (int rr = 0; rr < 8; ++rr)
#pragma unroll
                for (int b = 0; b < 2; ++b) {
                    int a = acc[rr][b];
                    a += __shfl_xor(a, 8, 64);
                    a += __shfl_xor(a, 16, 64);
                    a += __shfl_xor(a, 32, 64);
                    acc[rr][b] = a;
                }
            if (lane < 8) {                          // lane == rgrp, kslot 0
#pragma unroll
                for (int rr = 0; rr < 8; ++rr) {
                    red[par][w][lane][(rr << 1)]     = acc[rr][0];
                    red[par][w][lane][(rr << 1) + 1] = acc[rr][1];
                }
            }
        }
        __syncthreads();                             // the ONE barrier/step

        // ---- waves 0-1: final 8-way sum, fast tanh, tagged stores ----
        if (t < TSTEPS && tid < 128) {
            const int br = tid >> 1;                 // in-block row 0..63
            const int b  = tid & 1;
            int s = 0;
#pragma unroll
            for (int wp = 0; wp < 8; ++wp)
                s += red[par][wp][br >> 3][((br & 7) << 1) + b];
            float pre = (float)s * wscale[br] * (1.f / 127.f)
                      + wn0 * xv0 + wn1 * xv1 + wn2 * xv2;
            const int qv = q8_tanh127(pre);
            // pack rows (2u,2u+1) of batch bb into one tagged dword at the
            // FUSED address: flat = 64*rg + (u>>1)*4 + (u&1) + 2*bb
            const int qlo = __shfl(qv, ((lane >> 1) << 2) + (lane & 1), 64);
            const int qhi = __shfl(qv, ((lane >> 1) << 2) + 2 + (lane & 1), 64);
            if (lane < 32) {
                const int bb = lane & 1;
                const int u  = (w << 4) + (lane >> 1);   // 0..31 strip dword
                unsigned dv = (unsigned)(qlo & 0xff) |
                              ((unsigned)(qhi & 0xff) << 8) | (tg1 << 16);
                st1_uc(hbn + g * 2048 + 64 * rg + ((u >> 1) << 2)
                           + (u & 1) + (bb << 1), dv);
            }
        }

        // ---- off-path x prefetch for step t+1 (h-independent; lands
        // during the sleep+RT window, consumed post-barrier next iter)
        if (t + 1 < TSTEPS && tid < 128) {
            const float* xp = x + ((size_t)(b0 + (tid & 1)) * TSTEPS + (t + 1)) * NIN;
            xv0 = xp[0]; xv1 = xp[1]; xv2 = xp[2];
        }

        // ---- adaptive-delay cross-step prefetch (after stores) ----
        if (t < TSTEPS) {
            for (int i = 0; i < dly; ++i) __builtin_amdgcn_s_sleep(1);
            pf_issue4(tv, hbn + g * 2048 + woff);
        }

        // ---- waves 2-7: rotating projection (parallel with final/store).
        // r21-stride (r = j*64+lane): conflict-free scalar LDS reads,
        // coalesced Wout reads.
        if (t > 0 && rg == ((t - 1) & 31) && w >= 2) {
            const int pw = w - 2;                    // 0..5
            const int b  = pw / NOUT;                // 0..1
            const int k  = pw % NOUT;                // 0..2
            const signed char* hsv = (const signed char*)hstage[par][b];
            float a = 0.f;
#pragma unroll
            for (int j = 0; j < 32; ++j) {
                const int r = j * 64 + lane;
                a += (float)hsv[r] * Wout[k * RDIM + r];
            }
#pragma unroll
            for (int off = 32; off >= 1; off >>= 1)
                a += __shfl_xor(a, off, 64);
            if (lane == 0)
                out[((size_t)(b0 + b) * TSTEPS + (t - 1)) * NOUT + k] =
                    a * (1.f / 127.f) + bout[k];
        }
        // WAR safety unchanged: parity double-buffering + the per-step
        // barrier order all red/hstage read-write pairs.
    }
}

extern "C" void kernel_launch(void* const* d_in, const int* in_sizes, int n_in,
                              void* d_out, int out_size, void* d_ws, size_t ws_size,
                              hipStream_t stream) {
    const float* x    = (const float*)d_in[0];
    const float* Win  = (const float*)d_in[1];
    const float* W    = (const float*)d_in[2];
    const float* Wout = (const float*)d_in[3];
    const float* bout = (const float*)d_in[4];
    float* out = (float*)d_out;
    unsigned* wsu = (unsigned*)d_ws;

    // zero tagged-h buffers (tag0 + zero payload = valid h0), ~128 KB
    hipMemsetAsync(d_ws, 0, (size_t)WS_USED_DW * sizeof(unsigned), stream);

    // allow + allocate 128 KB dynamic LDS: UNUSED by the kernel, kept to
    // pin occupancy at 1 block/CU (without it 2 blocks could share a CU,
    // breaking the latency symmetry the exchange tuning relies on).
    hipFuncSetAttribute((const void*)esn_persist,
                        hipFuncAttributeMaxDynamicSharedMemorySize, 131072);

    void* args[] = {(void*)&W, (void*)&Win, (void*)&x, (void*)&Wout, (void*)&bout,
                    (void*)&wsu, (void*)&out};
    hipError_t e = hipLaunchCooperativeKernel((const void*)esn_persist,
                                              dim3(NBLK), dim3(NTHR),
                                              args, 131072, stream);
    if (e != hipSuccess) {
        // Fallback: plain launch (256 blocks, 1/CU with ~150KB LDS -> all
        // co-resident; bounded spins guarantee no hang regardless).
        esn_persist<<<dim3(NBLK), dim3(NTHR), 131072, stream>>>(
            W, Win, x, Wout, bout, wsu, out);
    }
}